// Round 7
// baseline (325.995 us; speedup 1.0000x reference)
//
#include <hip/hip_runtime.h>
#include <math.h>

#define BSZ 32
#define NA 3
#define NC 80
#define HH 64
#define WW 64
#define NT 50
#define NCH (NA*(5+NC))   // 255

constexpr int NCELL = BSZ*NA*HH*WW;   // 393216
constexpr float IGNORE_THR_C = 0.5f;
constexpr float CONST0 = 1e-12f;                 // -log1p(-EPS)
constexpr float CLAMPB = 27.631021115928547f;    // -log(EPS)

__device__ __forceinline__ float sigm(float x) { return 1.0f / (1.0f + __expf(-x)); }
// softplus(x) = log(1+e^x); equals -log(1-clip(sigm(x))) up to the CLAMPB clamp
__device__ __forceinline__ float softplus(float x) {
    return fmaxf(x, 0.0f) + __logf(1.0f + __expf(-fabsf(x)));
}
__device__ __forceinline__ float bce_t0(float v) { return fminf(softplus(v),  CLAMPB); } // -log(1-p)
__device__ __forceinline__ float bce_t1(float v) { return fminf(softplus(-v), CLAMPB); } // -log(p)

// ---------------- kernel 1: build target maps (1 block per batch, 1 lane per target) ----------------
__global__ __launch_bounds__(64) void k_targets(const float* __restrict__ inp, const float* __restrict__ tgt,
                          unsigned char* __restrict__ mask_b, unsigned char* __restrict__ ignore_b,
                          float* __restrict__ txa, float* __restrict__ tya,
                          float* __restrict__ twa, float* __restrict__ tha,
                          float* __restrict__ gwa, unsigned int* __restrict__ clsbits)
{
    const int b = blockIdx.x;
    const int t = threadIdx.x;      // lane == target index
    const float aw[3] = {1.25f, 2.0f, 4.125f};   // ANCHORS / stride(=8)
    const float ah[3] = {1.625f, 3.75f, 2.875f};

    bool valid = false;
    int cell = -1, ci = 0, gi = 0, gj = 0, best = 0;
    float gx = 0, gy = 0, gw = 0, gh = 0;

    if (t < NT) {
        const float* tg = tgt + (size_t)(b*NT + t)*5;
        float c0 = tg[0], c1 = tg[1], c2 = tg[2], c3 = tg[3], c4 = tg[4];
        valid = (c0 + c1 + c2 + c3 + c4) > 0.0f;
        if (valid) {
            gx = c1 * WW; gy = c2 * HH; gw = c3 * WW; gh = c4 * HH;
            gi = min(max((int)gx, 0), WW-1);
            gj = min(max((int)gy, 0), HH-1);
            float bestiou = -1.0f;
            #pragma unroll
            for (int a = 0; a < 3; ++a) {     // first max wins, like jnp.argmax
                float inter = fminf(gw, aw[a]) * fminf(gh, ah[a]);
                float iou = inter / (gw*gh + aw[a]*ah[a] - inter + 1e-16f);
                if (iou > bestiou) { bestiou = iou; best = a; }
            }
            cell = ((b*NA + best)*HH + gj)*WW + gi;
            ci = min(max((int)c0, 0), NC-1);
        }
    }

    // pred-IoU ignore flagging: races benign (all writers store 1)
    if (valid) {
        #pragma unroll
        for (int a = 0; a < 3; ++a) {
            size_t base = (((size_t)b*NCH + a*(5+NC))*HH + gj)*WW + gi;
            const size_t PL = (size_t)HH*WW;
            float px = sigm(inp[base + 0*PL]) + (float)gi;
            float py = sigm(inp[base + 1*PL]) + (float)gj;
            float pw = __expf(inp[base + 2*PL]) * aw[a];
            float ph = __expf(inp[base + 3*PL]) * ah[a];

            float b1x1 = gx - gw*0.5f, b1x2 = gx + gw*0.5f;
            float b1y1 = gy - gh*0.5f, b1y2 = gy + gh*0.5f;
            float b2x1 = px - pw*0.5f, b2x2 = px + pw*0.5f;
            float b2y1 = py - ph*0.5f, b2y2 = py + ph*0.5f;
            float iw = fmaxf(fminf(b1x2,b2x2) - fmaxf(b1x1,b2x1), 0.0f);
            float ih = fmaxf(fminf(b1y2,b2y2) - fmaxf(b1y1,b2y1), 0.0f);
            float inter = iw*ih;
            float a1 = (b1x2-b1x1)*(b1y2-b1y1);
            float a2 = (b2x2-b2x1)*(b2y2-b2y1);
            float piou = inter / (a1 + a2 - inter + 1e-16f);
            if (piou > IGNORE_THR_C) {
                ignore_b[((b*NA + a)*HH + gj)*WW + gi] = 1;
            }
        }
    }

    // winner = last valid t per cell (matches serial last-writer-wins);
    // class bits = union over all valid same-cell targets. All via wave shfl — no atomics.
    bool winner = valid;
    unsigned int b0 = 0, b1 = 0, b2 = 0;
    for (int u = 0; u < NT; ++u) {
        int cu = __shfl(cell, u, 64);
        int vu = __shfl((int)valid, u, 64);
        int cu_ci = __shfl(ci, u, 64);
        if (vu && cu == cell) {
            if (u > t) winner = false;
            if (cu_ci < 32)      b0 |= 1u << cu_ci;
            else if (cu_ci < 64) b1 |= 1u << (cu_ci - 32);
            else                 b2 |= 1u << (cu_ci - 64);
        }
    }

    if (winner) {
        mask_b[cell] = 1;
        clsbits[cell*3+0] = b0;
        clsbits[cell*3+1] = b1;
        clsbits[cell*3+2] = b2;
        txa[cell] = gx - (float)gi;
        tya[cell] = gy - (float)gj;
        twa[cell] = logf(gw / aw[best] + 1e-16f);
        tha[cell] = logf(gh / ah[best] + 1e-16f);
        gwa[cell] = sigm(gw) * sigm(gh);
    }
}

// ---------------- kernel 2: per-cell loss + wave-cooperative class BCE ----------------
// sums: [0]=x [1]=y [2]=w [3]=h [4]=conf_obj [5]=conf_noobj [6]=cls [7]=n_sel
// Unmasked cells' constant contributions to s0/s1/s4 (CONST0 each) are added analytically in k_final.
__global__ __launch_bounds__(256) void k_loss(const float* __restrict__ inp,
                       const unsigned char* __restrict__ mask_b,
                       const unsigned char* __restrict__ ignore_b,
                       const float* __restrict__ txa, const float* __restrict__ tya,
                       const float* __restrict__ twa, const float* __restrict__ tha,
                       const float* __restrict__ gwa,
                       const unsigned int* __restrict__ clsbits,
                       double* __restrict__ sums)
{
    const int n = blockIdx.x * blockDim.x + threadIdx.x;   // one cell per thread, grid == NCELL
    const int lane = threadIdx.x & 63;
    const size_t PL = (size_t)HH*WW;

    int i = n & (WW-1);
    int j = (n >> 6) & (HH-1);
    int a = (n >> 12) % NA;
    int b = n / (NA*HH*WW);
    size_t base = (((size_t)b*NCH + a*(5+NC))*HH + j)*WW + i;

    float conf = inp[base + 4*PL];
    bool m  = mask_b[n]   != 0;
    bool ig = ignore_b[n] != 0;

    float s0=0, s1=0, s2=0, s3=0, s4=0, s6=0, s7=0;
    float s5 = ig ? CONST0 : bce_t0(conf);

    unsigned int bb0 = 0, bb1 = 0, bb2 = 0;
    if (m) {
        float xv = inp[base + 0*PL];
        float yv = inp[base + 1*PL];
        float w  = inp[base + 2*PL];
        float h  = inp[base + 3*PL];
        float tx = txa[n], ty = tya[n], tw = twa[n], th = tha[n];
        float gwxh = gwa[n];

        s0 = tx*bce_t1(xv) + (1.0f - tx)*bce_t0(xv);
        s1 = ty*bce_t1(yv) + (1.0f - ty)*bce_t0(yv);
        float temp = (2.0f - gwxh); temp = temp*temp;
        float dw = (w - tw) * temp;  s2 = dw*dw;
        float dh = (h - th) * temp;  s3 = dh*dh;
        s4 = bce_t1(conf);
        s7 = 1.0f;
        bb0 = clsbits[n*3+0]; bb1 = clsbits[n*3+1]; bb2 = clsbits[n*3+2];
    }

    // wave-cooperative class BCE: for each masked lane, all 64 lanes split the 80 classes
    unsigned long long mb = __ballot(m);
    while (mb) {
        int src = __ffsll((long long)mb) - 1;
        mb &= mb - 1;
        int ns  = __shfl(n, src, 64);
        unsigned int c0 = __shfl(bb0, src, 64);
        unsigned int c1 = __shfl(bb1, src, 64);
        unsigned int c2 = __shfl(bb2, src, 64);

        int is = ns & (WW-1);
        int js = (ns >> 6) & (HH-1);
        int as_ = (ns >> 12) % NA;
        int bs = ns / (NA*HH*WW);
        size_t sbase = (((size_t)bs*NCH + as_*(5+NC))*HH + js)*WW + is;

        float part;
        {
            int c = lane;                                  // classes 0..63
            float p = inp[sbase + (size_t)(5+c)*PL];
            bool tc = (((c < 32) ? c0 : c1) >> (c & 31)) & 1u;
            part = tc ? bce_t1(p) : bce_t0(p);
        }
        if (lane < NC - 64) {                              // classes 64..79 on lanes 0..15
            int c = 64 + lane;
            float p = inp[sbase + (size_t)(5+c)*PL];
            bool tc = (c2 >> lane) & 1u;
            part += tc ? bce_t1(p) : bce_t0(p);
        }
        #pragma unroll
        for (int off = 32; off > 0; off >>= 1) part += __shfl_xor(part, off, 64);
        if (lane == src) s6 += part;
    }

    // block reduction: wave butterfly, cross-wave via LDS, one f64 atomic set per block
    float s[8] = {s0, s1, s2, s3, s4, s5, s6, s7};
    #pragma unroll
    for (int k = 0; k < 8; ++k) {
        float v = s[k];
        for (int off = 32; off > 0; off >>= 1) v += __shfl_down(v, off, 64);
        s[k] = v;
    }
    __shared__ float sh[4][8];
    int wv = threadIdx.x >> 6;
    if (lane == 0) {
        #pragma unroll
        for (int k = 0; k < 8; ++k) sh[wv][k] = s[k];
    }
    __syncthreads();
    if (threadIdx.x == 0) {
        #pragma unroll
        for (int k = 0; k < 8; ++k) {
            double v = (double)sh[0][k] + (double)sh[1][k] + (double)sh[2][k] + (double)sh[3][k];
            atomicAdd(&sums[k], v);
        }
    }
}

// ---------------- kernel 3: finalize ----------------
__global__ void k_final(const double* __restrict__ sums, float* __restrict__ out)
{
    if (blockIdx.x != 0 || threadIdx.x != 0) return;
    double N = (double)NCELL;
    double nsel = sums[7];
    double cpad = (double)CONST0 * (N - nsel);   // unmasked cells' constant BCE terms
    double lx = (sums[0] + cpad) / N;
    double ly = (sums[1] + cpad) / N;
    double lw = sums[2] / N;
    double lh = sums[3] / N;
    double lconf = (sums[4] + cpad) / N + 0.5 * (sums[5] / N);
    double lcls  = sums[6] / (nsel * NC + 1e-16);
    double loss = (lx + ly) * 2.5 + (lw + lh) * 2.5 + lconf * 1.0 + lcls * 1.0;
    out[0] = (float)loss;
    out[1] = (float)lx;
    out[2] = (float)ly;
    out[3] = (float)lw;
    out[4] = (float)lh;
    out[5] = (float)lconf;
    out[6] = (float)lcls;
}

extern "C" void kernel_launch(void* const* d_in, const int* in_sizes, int n_in,
                              void* d_out, int out_size, void* d_ws, size_t ws_size,
                              hipStream_t stream)
{
    const float* inp = (const float*)d_in[0];
    const float* tgt = (const float*)d_in[1];
    float* out = (float*)d_out;

    // layout: [sums 64B][mask NCELL][ignore NCELL] — zeroed in ONE memset;
    // [tx..gwa 5×NCELL f32][clsbits 3×NCELL u32] — only read where mask==1 (always written first)
    char* ws = (char*)d_ws;
    double* sums           = (double*)ws;
    unsigned char* mask_b  = (unsigned char*)(ws + 64);
    unsigned char* ignore_b= mask_b + NCELL;
    float* txa  = (float*)(ws + 64 + 2*(size_t)NCELL);
    float* tya  = txa + NCELL;
    float* twa  = tya + NCELL;
    float* tha  = twa + NCELL;
    float* gwa  = tha + NCELL;
    unsigned int* clsbits = (unsigned int*)(gwa + NCELL);

    hipMemsetAsync(ws, 0, 64 + 2*(size_t)NCELL, stream);

    k_targets<<<BSZ, 64, 0, stream>>>(inp, tgt, mask_b, ignore_b, txa, tya, twa, tha, gwa, clsbits);

    k_loss<<<NCELL/256, 256, 0, stream>>>(inp, mask_b, ignore_b, txa, tya, twa, tha, gwa, clsbits, sums);

    k_final<<<1, 64, 0, stream>>>(sums, out);
}

// Round 10
// 230.032 us; speedup vs baseline: 1.4172x; 1.4172x over previous
//
#include <hip/hip_runtime.h>
#include <math.h>

#define BSZ 32
#define NA 3
#define NC 80
#define HH 64
#define WW 64
#define NT 50
#define NCH (NA*(5+NC))   // 255

constexpr int NCELL = BSZ*NA*HH*WW;   // 393216
constexpr int NBLK  = NCELL/256;      // 1536 k_loss blocks
constexpr float IGNORE_THR_C = 0.5f;
constexpr float CONST0 = 1e-12f;                 // -log1p(-EPS)
constexpr float CLAMPB = 27.631021115928547f;    // -log(EPS)

__device__ __forceinline__ float sigm(float x) { return 1.0f / (1.0f + __expf(-x)); }
// softplus(x) = log(1+e^x); equals -log(1-clip(sigm(x))) up to the CLAMPB clamp
__device__ __forceinline__ float softplus(float x) {
    return fmaxf(x, 0.0f) + __logf(1.0f + __expf(-fabsf(x)));
}
__device__ __forceinline__ float bce_t0(float v) { return fminf(softplus(v),  CLAMPB); } // -log(1-p)
__device__ __forceinline__ float bce_t1(float v) { return fminf(softplus(-v), CLAMPB); } // -log(p)

// ---------------- kernel 1: build target maps (1 block per batch, 1 lane per target) ----------------
__global__ __launch_bounds__(64) void k_targets(const float* __restrict__ inp, const float* __restrict__ tgt,
                          unsigned char* __restrict__ mask_b, unsigned char* __restrict__ ignore_b,
                          float* __restrict__ txa, float* __restrict__ tya,
                          float* __restrict__ twa, float* __restrict__ tha,
                          float* __restrict__ gwa, unsigned int* __restrict__ clsbits)
{
    const int b = blockIdx.x;
    const int t = threadIdx.x;      // lane == target index
    const float aw[3] = {1.25f, 2.0f, 4.125f};   // ANCHORS / stride(=8)
    const float ah[3] = {1.625f, 3.75f, 2.875f};

    bool valid = false;
    int cell = -1, ci = 0, gi = 0, gj = 0, best = 0;
    float gx = 0, gy = 0, gw = 0, gh = 0;

    if (t < NT) {
        const float* tg = tgt + (size_t)(b*NT + t)*5;
        float c0 = tg[0], c1 = tg[1], c2 = tg[2], c3 = tg[3], c4 = tg[4];
        valid = (c0 + c1 + c2 + c3 + c4) > 0.0f;
        if (valid) {
            gx = c1 * WW; gy = c2 * HH; gw = c3 * WW; gh = c4 * HH;
            gi = min(max((int)gx, 0), WW-1);
            gj = min(max((int)gy, 0), HH-1);
            float bestiou = -1.0f;
            #pragma unroll
            for (int a = 0; a < 3; ++a) {     // first max wins, like jnp.argmax
                float inter = fminf(gw, aw[a]) * fminf(gh, ah[a]);
                float iou = inter / (gw*gh + aw[a]*ah[a] - inter + 1e-16f);
                if (iou > bestiou) { bestiou = iou; best = a; }
            }
            cell = ((b*NA + best)*HH + gj)*WW + gi;
            ci = min(max((int)c0, 0), NC-1);
        }
    }

    // pred-IoU ignore flagging: races benign (all writers store 1)
    if (valid) {
        #pragma unroll
        for (int a = 0; a < 3; ++a) {
            size_t base = (((size_t)b*NCH + a*(5+NC))*HH + gj)*WW + gi;
            const size_t PL = (size_t)HH*WW;
            float px = sigm(inp[base + 0*PL]) + (float)gi;
            float py = sigm(inp[base + 1*PL]) + (float)gj;
            float pw = __expf(inp[base + 2*PL]) * aw[a];
            float ph = __expf(inp[base + 3*PL]) * ah[a];

            float b1x1 = gx - gw*0.5f, b1x2 = gx + gw*0.5f;
            float b1y1 = gy - gh*0.5f, b1y2 = gy + gh*0.5f;
            float b2x1 = px - pw*0.5f, b2x2 = px + pw*0.5f;
            float b2y1 = py - ph*0.5f, b2y2 = py + ph*0.5f;
            float iw = fmaxf(fminf(b1x2,b2x2) - fmaxf(b1x1,b2x1), 0.0f);
            float ih = fmaxf(fminf(b1y2,b2y2) - fmaxf(b1y1,b2y1), 0.0f);
            float inter = iw*ih;
            float a1 = (b1x2-b1x1)*(b1y2-b1y1);
            float a2 = (b2x2-b2x1)*(b2y2-b2y1);
            float piou = inter / (a1 + a2 - inter + 1e-16f);
            if (piou > IGNORE_THR_C) {
                ignore_b[((b*NA + a)*HH + gj)*WW + gi] = 1;
            }
        }
    }

    // winner = last valid t per cell (matches serial last-writer-wins);
    // class bits = union over all valid same-cell targets. All via wave shfl — no atomics.
    bool winner = valid;
    unsigned int b0 = 0, b1 = 0, b2 = 0;
    for (int u = 0; u < NT; ++u) {
        int cu = __shfl(cell, u, 64);
        int vu = __shfl((int)valid, u, 64);
        int cu_ci = __shfl(ci, u, 64);
        if (vu && cu == cell) {
            if (u > t) winner = false;
            if (cu_ci < 32)      b0 |= 1u << cu_ci;
            else if (cu_ci < 64) b1 |= 1u << (cu_ci - 32);
            else                 b2 |= 1u << (cu_ci - 64);
        }
    }

    if (winner) {
        mask_b[cell] = 1;
        clsbits[cell*3+0] = b0;
        clsbits[cell*3+1] = b1;
        clsbits[cell*3+2] = b2;
        txa[cell] = gx - (float)gi;
        tya[cell] = gy - (float)gj;
        twa[cell] = logf(gw / aw[best] + 1e-16f);
        tha[cell] = logf(gh / ah[best] + 1e-16f);
        gwa[cell] = sigm(gw) * sigm(gh);
    }
}

// ---------------- kernel 2: per-cell loss + wave-cooperative class BCE ----------------
// per-block partials: [0]=x [1]=y [2]=w [3]=h [4]=conf_obj [5]=conf_noobj [6]=cls [7]=n_sel
// Plain stores to partials[blockIdx.x][8] — NO global atomics (f64 atomicAdd = CAS loop,
// 12288 contended CAS on one line was 154 µs of pure stall in R7).
__global__ __launch_bounds__(256) void k_loss(const float* __restrict__ inp,
                       const unsigned char* __restrict__ mask_b,
                       const unsigned char* __restrict__ ignore_b,
                       const float* __restrict__ txa, const float* __restrict__ tya,
                       const float* __restrict__ twa, const float* __restrict__ tha,
                       const float* __restrict__ gwa,
                       const unsigned int* __restrict__ clsbits,
                       float* __restrict__ partials)
{
    const int n = blockIdx.x * blockDim.x + threadIdx.x;   // one cell per thread, grid == NCELL
    const int lane = threadIdx.x & 63;
    const size_t PL = (size_t)HH*WW;

    int i = n & (WW-1);
    int j = (n >> 6) & (HH-1);
    int a = (n >> 12) % NA;
    int b = n / (NA*HH*WW);
    size_t base = (((size_t)b*NCH + a*(5+NC))*HH + j)*WW + i;

    float conf = inp[base + 4*PL];
    bool m  = mask_b[n]   != 0;
    bool ig = ignore_b[n] != 0;

    float s0=0, s1=0, s2=0, s3=0, s4=0, s6=0, s7=0;
    float s5 = ig ? CONST0 : bce_t0(conf);

    unsigned int bb0 = 0, bb1 = 0, bb2 = 0;
    if (m) {
        float xv = inp[base + 0*PL];
        float yv = inp[base + 1*PL];
        float w  = inp[base + 2*PL];
        float h  = inp[base + 3*PL];
        float tx = txa[n], ty = tya[n], tw = twa[n], th = tha[n];
        float gwxh = gwa[n];

        s0 = tx*bce_t1(xv) + (1.0f - tx)*bce_t0(xv);
        s1 = ty*bce_t1(yv) + (1.0f - ty)*bce_t0(yv);
        float temp = (2.0f - gwxh); temp = temp*temp;
        float dw = (w - tw) * temp;  s2 = dw*dw;
        float dh = (h - th) * temp;  s3 = dh*dh;
        s4 = bce_t1(conf);
        s7 = 1.0f;
        bb0 = clsbits[n*3+0]; bb1 = clsbits[n*3+1]; bb2 = clsbits[n*3+2];
    }

    // wave-cooperative class BCE: for each masked lane, all 64 lanes split the 80 classes
    unsigned long long mb = __ballot(m);
    while (mb) {
        int src = __ffsll((long long)mb) - 1;
        mb &= mb - 1;
        int ns  = __shfl(n, src, 64);
        unsigned int c0 = __shfl(bb0, src, 64);
        unsigned int c1 = __shfl(bb1, src, 64);
        unsigned int c2 = __shfl(bb2, src, 64);

        int is = ns & (WW-1);
        int js = (ns >> 6) & (HH-1);
        int as_ = (ns >> 12) % NA;
        int bs = ns / (NA*HH*WW);
        size_t sbase = (((size_t)bs*NCH + as_*(5+NC))*HH + js)*WW + is;

        float part;
        {
            int c = lane;                                  // classes 0..63
            float p = inp[sbase + (size_t)(5+c)*PL];
            bool tc = (((c < 32) ? c0 : c1) >> (c & 31)) & 1u;
            part = tc ? bce_t1(p) : bce_t0(p);
        }
        if (lane < NC - 64) {                              // classes 64..79 on lanes 0..15
            int c = 64 + lane;
            float p = inp[sbase + (size_t)(5+c)*PL];
            bool tc = (c2 >> lane) & 1u;
            part += tc ? bce_t1(p) : bce_t0(p);
        }
        #pragma unroll
        for (int off = 32; off > 0; off >>= 1) part += __shfl_xor(part, off, 64);
        if (lane == src) s6 += part;
    }

    // block reduction: wave butterfly, cross-wave via LDS, plain stores of block partials
    float s[8] = {s0, s1, s2, s3, s4, s5, s6, s7};
    #pragma unroll
    for (int k = 0; k < 8; ++k) {
        float v = s[k];
        for (int off = 32; off > 0; off >>= 1) v += __shfl_down(v, off, 64);
        s[k] = v;
    }
    __shared__ float sh[4][8];
    int wv = threadIdx.x >> 6;
    if (lane == 0) {
        #pragma unroll
        for (int k = 0; k < 8; ++k) sh[wv][k] = s[k];
    }
    __syncthreads();
    if (threadIdx.x < 8) {
        int k = threadIdx.x;
        partials[blockIdx.x*8 + k] = sh[0][k] + sh[1][k] + sh[2][k] + sh[3][k];
    }
}

// ---------------- kernel 3: reduce partials + finalize (1 wave) ----------------
__global__ __launch_bounds__(64) void k_final(const float* __restrict__ partials,
                                              float* __restrict__ out)
{
    const int lane = threadIdx.x;
    const int k = lane & 7;        // which of the 8 terms
    double part = 0.0;
    for (int i = lane >> 3; i < NBLK; i += 8)   // 8 lanes per term, strided over blocks
        part += (double)partials[i*8 + k];
    // combine the 8 lanes holding the same k (they differ in bits 3..5 of lane)
    part += __shfl_xor(part, 8, 64);
    part += __shfl_xor(part, 16, 64);
    part += __shfl_xor(part, 32, 64);
    // lanes 0..7 hold full sums for k=0..7.

    // Gather to ALL lanes while the whole wave is still active — __shfl from an
    // inactive lane is undefined (R8 bug: these shfls sat inside `if(lane==0)`).
    double s0 = __shfl(part, 0, 64);
    double s1 = __shfl(part, 1, 64);
    double s2 = __shfl(part, 2, 64);
    double s3 = __shfl(part, 3, 64);
    double s4 = __shfl(part, 4, 64);
    double s5 = __shfl(part, 5, 64);
    double s6 = __shfl(part, 6, 64);
    double s7 = __shfl(part, 7, 64);

    if (lane == 0) {
        double N = (double)NCELL;
        double nsel = s7;
        double cpad = (double)CONST0 * (N - nsel);   // unmasked cells' constant BCE terms
        double lx = (s0 + cpad) / N;
        double ly = (s1 + cpad) / N;
        double lw = s2 / N;
        double lh = s3 / N;
        double lconf = (s4 + cpad) / N + 0.5 * (s5 / N);
        double lcls  = s6 / (nsel * NC + 1e-16);
        double loss = (lx + ly) * 2.5 + (lw + lh) * 2.5 + lconf * 1.0 + lcls * 1.0;
        out[0] = (float)loss;
        out[1] = (float)lx;
        out[2] = (float)ly;
        out[3] = (float)lw;
        out[4] = (float)lh;
        out[5] = (float)lconf;
        out[6] = (float)lcls;
    }
}

extern "C" void kernel_launch(void* const* d_in, const int* in_sizes, int n_in,
                              void* d_out, int out_size, void* d_ws, size_t ws_size,
                              hipStream_t stream)
{
    const float* inp = (const float*)d_in[0];
    const float* tgt = (const float*)d_in[1];
    float* out = (float*)d_out;

    // layout: [partials NBLK*8 f32][mask NCELL][ignore NCELL] — mask/ignore zeroed in ONE memset
    // (partials fully overwritten by k_loss every launch — no clearing needed);
    // [tx..gwa 5×NCELL f32][clsbits 3×NCELL u32] — only read where mask==1 (always written first)
    char* ws = (char*)d_ws;
    float* partials        = (float*)ws;                          // NBLK*8 = 12288 f32 (48 KB)
    unsigned char* mask_b  = (unsigned char*)(ws + NBLK*8*sizeof(float));
    unsigned char* ignore_b= mask_b + NCELL;
    float* txa  = (float*)(ws + NBLK*8*sizeof(float) + 2*(size_t)NCELL);
    float* tya  = txa + NCELL;
    float* twa  = tya + NCELL;
    float* tha  = twa + NCELL;
    float* gwa  = tha + NCELL;
    unsigned int* clsbits = (unsigned int*)(gwa + NCELL);

    hipMemsetAsync(mask_b, 0, 2*(size_t)NCELL, stream);

    k_targets<<<BSZ, 64, 0, stream>>>(inp, tgt, mask_b, ignore_b, txa, tya, twa, tha, gwa, clsbits);

    k_loss<<<NBLK, 256, 0, stream>>>(inp, mask_b, ignore_b, txa, tya, twa, tha, gwa, clsbits, partials);

    k_final<<<1, 64, 0, stream>>>(partials, out);
}